// Round 1
// baseline (2223.056 us; speedup 1.0000x reference)
//
#include <hip/hip_runtime.h>
#include <math.h>

#define N_NODES 100000
#define N_EDGES 3200000
#define D_FEAT  512
#define D_HID   64
#define N_CLS   40

// ---------------- degree / norm ----------------

__global__ __launch_bounds__(256) void k_deg_init(float* __restrict__ deg) {
    int n = blockIdx.x * 256 + threadIdx.x;
    if (n < N_NODES) deg[n] = 1.0f;   // self-loop weight 1
}

__global__ __launch_bounds__(256) void k_deg_accum(const int* __restrict__ ei,
                                                   const float* __restrict__ ew,
                                                   float* __restrict__ deg) {
    int e = blockIdx.x * 256 + threadIdx.x;
    if (e < N_EDGES) unsafeAtomicAdd(&deg[ei[N_EDGES + e]], ew[e]);
}

__global__ __launch_bounds__(256) void k_dinv(const float* __restrict__ deg,
                                              float* __restrict__ dinv) {
    int n = blockIdx.x * 256 + threadIdx.x;
    if (n < N_NODES) dinv[n] = rsqrtf(deg[n]);   // deg >= 1 always
}

// ---------------- layer 1 GEMM: hpre = x @ W1, agg1 = dinv^2 * hpre ----------------
// block = 256 threads = 4 waves; each wave computes 4 rows x 64 cols; block = 16 rows.
// 100000 / 16 = 6250 blocks exactly.

__global__ __launch_bounds__(256) void k_gemm1(const float* __restrict__ x,
                                               const float* __restrict__ W1,
                                               const float* __restrict__ dinv,
                                               float* __restrict__ hpre,
                                               float* __restrict__ agg1) {
    const int col = threadIdx.x & 63;
    const int rg  = threadIdx.x >> 6;          // 0..3
    const int r0  = blockIdx.x * 16 + rg * 4;  // rows r0 .. r0+3

    const float* xp0 = x + (size_t)(r0 + 0) * D_FEAT;
    const float* xp1 = x + (size_t)(r0 + 1) * D_FEAT;
    const float* xp2 = x + (size_t)(r0 + 2) * D_FEAT;
    const float* xp3 = x + (size_t)(r0 + 3) * D_FEAT;

    float a0 = 0.f, a1 = 0.f, a2 = 0.f, a3 = 0.f;
    for (int k = 0; k < D_FEAT; k += 4) {
        float w0 = W1[(k + 0) * D_HID + col];
        float w1 = W1[(k + 1) * D_HID + col];
        float w2 = W1[(k + 2) * D_HID + col];
        float w3 = W1[(k + 3) * D_HID + col];
        float4 xa = *(const float4*)(xp0 + k);
        float4 xb = *(const float4*)(xp1 + k);
        float4 xc = *(const float4*)(xp2 + k);
        float4 xd = *(const float4*)(xp3 + k);
        a0 += xa.x * w0 + xa.y * w1 + xa.z * w2 + xa.w * w3;
        a1 += xb.x * w0 + xb.y * w1 + xb.z * w2 + xb.w * w3;
        a2 += xc.x * w0 + xc.y * w1 + xc.z * w2 + xc.w * w3;
        a3 += xd.x * w0 + xd.y * w1 + xd.z * w2 + xd.w * w3;
    }

    float d0 = dinv[r0 + 0], d1 = dinv[r0 + 1], d2 = dinv[r0 + 2], d3 = dinv[r0 + 3];
    hpre[(size_t)(r0 + 0) * D_HID + col] = a0;
    hpre[(size_t)(r0 + 1) * D_HID + col] = a1;
    hpre[(size_t)(r0 + 2) * D_HID + col] = a2;
    hpre[(size_t)(r0 + 3) * D_HID + col] = a3;
    agg1[(size_t)(r0 + 0) * D_HID + col] = d0 * d0 * a0;  // self-loop: norm = dinv^2 * 1
    agg1[(size_t)(r0 + 1) * D_HID + col] = d1 * d1 * a1;
    agg1[(size_t)(r0 + 2) * D_HID + col] = d2 * d2 * a2;
    agg1[(size_t)(r0 + 3) * D_HID + col] = d3 * d3 * a3;
}

// ---------------- layer 1 scatter: agg1[col] += norm * hpre[row] ----------------
// 64 lanes per edge (lane = feature). 3.2M * 64 / 256 = 800000 blocks exactly.

__global__ __launch_bounds__(256) void k_scatter1(const int* __restrict__ ei,
                                                  const float* __restrict__ ew,
                                                  const float* __restrict__ dinv,
                                                  const float* __restrict__ hpre,
                                                  float* __restrict__ agg1) {
    unsigned int gid = blockIdx.x * 256u + threadIdx.x;
    int lane = gid & 63;
    int e    = gid >> 6;
    int r = ei[e];
    int c = ei[N_EDGES + e];
    float nrm = dinv[r] * ew[e] * dinv[c];
    float v = nrm * hpre[(size_t)r * D_HID + lane];
    unsafeAtomicAdd(&agg1[(size_t)c * D_HID + lane], v);
}

// ---------------- layer 2 GEMM: z = relu(agg1 + b1) @ W2, agg2 = dinv^2 * z ----------------
// thread per (node, class). 100000*40 / 256 = 15625 blocks exactly.

__global__ __launch_bounds__(256) void k_gemm2(const float* __restrict__ agg1,
                                               const float* __restrict__ b1,
                                               const float* __restrict__ W2,
                                               const float* __restrict__ dinv,
                                               float* __restrict__ z,
                                               float* __restrict__ agg2) {
    int gid = blockIdx.x * 256 + threadIdx.x;
    int n = gid / N_CLS;
    int c = gid - n * N_CLS;
    const float* ap = agg1 + (size_t)n * D_HID;
    float acc = 0.f;
#pragma unroll 8
    for (int k = 0; k < D_HID; k++) {
        float h = ap[k] + b1[k];
        h = h > 0.f ? h : 0.f;
        acc += h * W2[k * N_CLS + c];
    }
    z[gid] = acc;
    float d = dinv[n];
    agg2[gid] = d * d * acc;   // self-loop contribution
}

// ---------------- layer 2 scatter: agg2[col] += norm * z[row] ----------------
// flat thread per (edge, class). 3.2M * 40 / 256 = 500000 blocks exactly.

__global__ __launch_bounds__(256) void k_scatter2(const int* __restrict__ ei,
                                                  const float* __restrict__ ew,
                                                  const float* __restrict__ dinv,
                                                  const float* __restrict__ z,
                                                  float* __restrict__ agg2) {
    unsigned int gid = blockIdx.x * 256u + threadIdx.x;
    int e = gid / N_CLS;
    int c = gid - e * N_CLS;
    int r  = ei[e];
    int cc = ei[N_EDGES + e];
    float nrm = dinv[r] * ew[e] * dinv[cc];
    unsafeAtomicAdd(&agg2[(size_t)cc * N_CLS + c], nrm * z[(size_t)r * N_CLS + c]);
}

// ---------------- log_softmax over 40 classes, wave per node ----------------
// 100000 / 4 = 25000 blocks exactly.

__global__ __launch_bounds__(256) void k_logsoftmax(const float* __restrict__ agg2,
                                                    const float* __restrict__ b2,
                                                    float* __restrict__ out) {
    int lane = threadIdx.x & 63;
    int n = blockIdx.x * 4 + (threadIdx.x >> 6);
    float v = -INFINITY;
    if (lane < N_CLS) v = agg2[(size_t)n * N_CLS + lane] + b2[lane];
    float m = v;
    for (int off = 32; off; off >>= 1) m = fmaxf(m, __shfl_xor(m, off, 64));
    float ev = (lane < N_CLS) ? expf(v - m) : 0.f;
    float s = ev;
    for (int off = 32; off; off >>= 1) s += __shfl_xor(s, off, 64);
    if (lane < N_CLS) out[(size_t)n * N_CLS + lane] = v - m - logf(s);
}

// ---------------- launch ----------------

extern "C" void kernel_launch(void* const* d_in, const int* in_sizes, int n_in,
                              void* d_out, int out_size, void* d_ws, size_t ws_size,
                              hipStream_t stream) {
    const float* x  = (const float*)d_in[0];
    const int*   ei = (const int*)d_in[1];     // [2, E] int32
    const float* ew = (const float*)d_in[2];
    const float* W1 = (const float*)d_in[3];
    const float* b1 = (const float*)d_in[4];
    const float* W2 = (const float*)d_in[5];
    const float* b2 = (const float*)d_in[6];
    float* out = (float*)d_out;

    // workspace layout (floats):
    //   deg  : N
    //   dinv : N
    //   hpre : N*64   (reused as agg2 after scatter1 — hpre dead once gemm2 starts? no:
    //                  hpre dead after k_scatter1; agg2 written in k_gemm2. safe.)
    //   agg1 : N*64
    //   z    : N*40
    float* ws   = (float*)d_ws;
    float* deg  = ws;
    float* dinv = deg + N_NODES;
    float* hpre = dinv + N_NODES;
    float* agg1 = hpre + (size_t)N_NODES * D_HID;
    float* z    = agg1 + (size_t)N_NODES * D_HID;
    float* agg2 = hpre;   // alias: hpre is dead after k_scatter1 completes

    k_deg_init <<<(N_NODES + 255) / 256, 256, 0, stream>>>(deg);
    k_deg_accum<<<N_EDGES / 256,          256, 0, stream>>>(ei, ew, deg);
    k_dinv     <<<(N_NODES + 255) / 256, 256, 0, stream>>>(deg, dinv);
    k_gemm1    <<<N_NODES / 16,           256, 0, stream>>>(x, W1, dinv, hpre, agg1);
    k_scatter1 <<<(unsigned)N_EDGES * 64 / 256, 256, 0, stream>>>(ei, ew, dinv, hpre, agg1);
    k_gemm2    <<<N_NODES * N_CLS / 256,  256, 0, stream>>>(agg1, b1, W2, dinv, z, agg2);
    k_scatter2 <<<(unsigned)N_EDGES * N_CLS / 256, 256, 0, stream>>>(ei, ew, dinv, z, agg2);
    k_logsoftmax<<<N_NODES / 4,           256, 0, stream>>>(agg2, b2, out);
}

// Round 2
// 1650.929 us; speedup vs baseline: 1.3465x; 1.3465x over previous
//
#include <hip/hip_runtime.h>
#include <math.h>

#define N_NODES 100000
#define N_EDGES 3200000
#define D_FEAT  512
#define D_HID   64
#define N_CLS   40
#define SCAN_NB ((N_NODES + 255) / 256)   /* 391 */

static __device__ __forceinline__ unsigned short f2bf(float f) {
    unsigned u = __float_as_uint(f);
    unsigned r = (u + 0x7FFFu + ((u >> 16) & 1u)) >> 16;   // RNE
    return (unsigned short)r;
}
static __device__ __forceinline__ float bf2f(unsigned short h) {
    return __uint_as_float(((unsigned)h) << 16);
}

// ---------------- degree + in-degree count ----------------

__global__ __launch_bounds__(256) void k_init(float* __restrict__ deg, int* __restrict__ cnt) {
    int n = blockIdx.x * 256 + threadIdx.x;
    if (n < N_NODES) { deg[n] = 1.0f; cnt[n] = 0; }   // self-loop weight 1
}

__global__ __launch_bounds__(256) void k_count(const int* __restrict__ ei,
                                               const float* __restrict__ ew,
                                               float* __restrict__ deg,
                                               int* __restrict__ cnt) {
    int e = blockIdx.x * 256 + threadIdx.x;
    int c = ei[N_EDGES + e];
    atomicAdd(&cnt[c], 1);
    unsafeAtomicAdd(&deg[c], ew[e]);
}

// ---------------- exclusive scan of cnt -> base (3 kernels) ----------------

__global__ __launch_bounds__(256) void k_scan1(const int* __restrict__ cnt,
                                               int* __restrict__ base,
                                               int* __restrict__ bsum) {
    __shared__ int s[256];
    int tid = threadIdx.x;
    int i = blockIdx.x * 256 + tid;
    int v = (i < N_NODES) ? cnt[i] : 0;
    s[tid] = v;
    __syncthreads();
    for (int off = 1; off < 256; off <<= 1) {
        int t = (tid >= off) ? s[tid - off] : 0;
        __syncthreads();
        s[tid] += t;
        __syncthreads();
    }
    if (i < N_NODES) base[i] = s[tid] - v;      // exclusive
    if (tid == 255) bsum[blockIdx.x] = s[255];  // block total
}

__global__ __launch_bounds__(512) void k_scan2(int* __restrict__ bsum) {
    __shared__ int s[512];
    int tid = threadIdx.x;
    int v = (tid < SCAN_NB) ? bsum[tid] : 0;
    s[tid] = v;
    __syncthreads();
    for (int off = 1; off < 512; off <<= 1) {
        int t = (tid >= off) ? s[tid - off] : 0;
        __syncthreads();
        s[tid] += t;
        __syncthreads();
    }
    bsum[tid] = s[tid] - v;                     // exclusive block offsets
}

__global__ __launch_bounds__(256) void k_scan3(int* __restrict__ base,
                                               int* __restrict__ cursor,
                                               const int* __restrict__ bsum,
                                               const float* __restrict__ deg,
                                               float* __restrict__ dinv) {
    int i = blockIdx.x * 256 + threadIdx.x;
    if (i < N_NODES) {
        int b = base[i] + bsum[blockIdx.x];
        base[i] = b;
        cursor[i] = b;
        dinv[i] = rsqrtf(deg[i]);               // deg >= 1 always
    }
}

// ---------------- CSR fill: (src, norm) per incoming edge, bucketed by dst ----------------

__global__ __launch_bounds__(256) void k_fill(const int* __restrict__ ei,
                                              const float* __restrict__ ew,
                                              const float* __restrict__ dinv,
                                              int* __restrict__ cursor,
                                              int2* __restrict__ csr) {
    int e = blockIdx.x * 256 + threadIdx.x;
    int r = ei[e];
    int c = ei[N_EDGES + e];
    float nrm = dinv[r] * ew[e] * dinv[c];
    int slot = atomicAdd(&cursor[c], 1);
    csr[slot] = make_int2(r, __float_as_int(nrm));
}

// ---------------- layer 1 GEMM: hpre(bf16) = x @ W1 ----------------
// block = 4 waves, wave computes 4 rows x 64 cols. 6250 blocks.

__global__ __launch_bounds__(256) void k_gemm1(const float* __restrict__ x,
                                               const float* __restrict__ W1,
                                               unsigned short* __restrict__ hpre) {
    const int col = threadIdx.x & 63;
    const int rg  = threadIdx.x >> 6;
    const int r0  = blockIdx.x * 16 + rg * 4;

    const float* xp0 = x + (size_t)(r0 + 0) * D_FEAT;
    const float* xp1 = x + (size_t)(r0 + 1) * D_FEAT;
    const float* xp2 = x + (size_t)(r0 + 2) * D_FEAT;
    const float* xp3 = x + (size_t)(r0 + 3) * D_FEAT;

    float a0 = 0.f, a1 = 0.f, a2 = 0.f, a3 = 0.f;
    for (int k = 0; k < D_FEAT; k += 4) {
        float w0 = W1[(k + 0) * D_HID + col];
        float w1 = W1[(k + 1) * D_HID + col];
        float w2 = W1[(k + 2) * D_HID + col];
        float w3 = W1[(k + 3) * D_HID + col];
        float4 xa = *(const float4*)(xp0 + k);
        float4 xb = *(const float4*)(xp1 + k);
        float4 xc = *(const float4*)(xp2 + k);
        float4 xd = *(const float4*)(xp3 + k);
        a0 += xa.x * w0 + xa.y * w1 + xa.z * w2 + xa.w * w3;
        a1 += xb.x * w0 + xb.y * w1 + xb.z * w2 + xb.w * w3;
        a2 += xc.x * w0 + xc.y * w1 + xc.z * w2 + xc.w * w3;
        a3 += xd.x * w0 + xd.y * w1 + xd.z * w2 + xd.w * w3;
    }
    hpre[(size_t)(r0 + 0) * D_HID + col] = f2bf(a0);
    hpre[(size_t)(r0 + 1) * D_HID + col] = f2bf(a1);
    hpre[(size_t)(r0 + 2) * D_HID + col] = f2bf(a2);
    hpre[(size_t)(r0 + 3) * D_HID + col] = f2bf(a3);
}

// ---------------- layer 1 gather: agg1[n] = d^2*hpre[n] + sum nrm*hpre[src] ----------------
// wave per node, lane = feature. 25000 blocks.

__global__ __launch_bounds__(256) void k_gather1(const int* __restrict__ base,
                                                 const int* __restrict__ cursor,
                                                 const int2* __restrict__ csr,
                                                 const unsigned short* __restrict__ hpre,
                                                 const float* __restrict__ dinv,
                                                 float* __restrict__ agg1) {
    int lane = threadIdx.x & 63;
    int n = blockIdx.x * 4 + (threadIdx.x >> 6);
    int s = base[n], e = cursor[n];   // cursor == end after fill
    float d = dinv[n];
    float acc0 = d * d * bf2f(hpre[(size_t)n * D_HID + lane]);
    float acc1 = 0.f;
    int j = s;
    for (; j + 1 < e; j += 2) {
        int2 p0 = csr[j];
        int2 p1 = csr[j + 1];
        acc0 += __int_as_float(p0.y) * bf2f(hpre[(size_t)p0.x * D_HID + lane]);
        acc1 += __int_as_float(p1.y) * bf2f(hpre[(size_t)p1.x * D_HID + lane]);
    }
    if (j < e) {
        int2 p = csr[j];
        acc0 += __int_as_float(p.y) * bf2f(hpre[(size_t)p.x * D_HID + lane]);
    }
    agg1[(size_t)n * D_HID + lane] = acc0 + acc1;
}

// ---------------- layer 2 GEMM: z = relu(agg1 + b1) @ W2 ----------------
// thread per (node, class). 15625 blocks.

__global__ __launch_bounds__(256) void k_gemm2(const float* __restrict__ agg1,
                                               const float* __restrict__ b1,
                                               const float* __restrict__ W2,
                                               float* __restrict__ z) {
    int gid = blockIdx.x * 256 + threadIdx.x;
    int n = gid / N_CLS;
    int c = gid - n * N_CLS;
    const float* ap = agg1 + (size_t)n * D_HID;
    float acc = 0.f;
#pragma unroll 8
    for (int k = 0; k < D_HID; k++) {
        float h = ap[k] + b1[k];
        h = h > 0.f ? h : 0.f;
        acc += h * W2[k * N_CLS + c];
    }
    z[gid] = acc;
}

// ---------------- layer 2 gather + bias + log_softmax fused ----------------
// wave per node, lanes < 40 active for features. 25000 blocks.

__global__ __launch_bounds__(256) void k_gather2_lsm(const int* __restrict__ base,
                                                     const int* __restrict__ cursor,
                                                     const int2* __restrict__ csr,
                                                     const float* __restrict__ z,
                                                     const float* __restrict__ dinv,
                                                     const float* __restrict__ b2,
                                                     float* __restrict__ out) {
    int lane = threadIdx.x & 63;
    int n = blockIdx.x * 4 + (threadIdx.x >> 6);
    bool act = lane < N_CLS;
    int fl = act ? lane : (N_CLS - 1);          // clamped lane for safe loads
    int s = base[n], e = cursor[n];
    float d = dinv[n];
    float acc0 = d * d * z[(size_t)n * N_CLS + fl];
    float acc1 = 0.f;
    int j = s;
    for (; j + 1 < e; j += 2) {
        int2 p0 = csr[j];
        int2 p1 = csr[j + 1];
        acc0 += __int_as_float(p0.y) * z[(size_t)p0.x * N_CLS + fl];
        acc1 += __int_as_float(p1.y) * z[(size_t)p1.x * N_CLS + fl];
    }
    if (j < e) {
        int2 p = csr[j];
        acc0 += __int_as_float(p.y) * z[(size_t)p.x * N_CLS + fl];
    }
    float logit = acc0 + acc1 + b2[fl];         // junk in lanes >= 40, masked below
    float m = act ? logit : -INFINITY;
    for (int off = 32; off; off >>= 1) m = fmaxf(m, __shfl_xor(m, off, 64));
    float ev = act ? expf(logit - m) : 0.f;
    float sum = ev;
    for (int off = 32; off; off >>= 1) sum += __shfl_xor(sum, off, 64);
    if (act) out[(size_t)n * N_CLS + lane] = logit - m - logf(sum);
}

// ---------------- launch ----------------

extern "C" void kernel_launch(void* const* d_in, const int* in_sizes, int n_in,
                              void* d_out, int out_size, void* d_ws, size_t ws_size,
                              hipStream_t stream) {
    const float* x  = (const float*)d_in[0];
    const int*   ei = (const int*)d_in[1];
    const float* ew = (const float*)d_in[2];
    const float* W1 = (const float*)d_in[3];
    const float* b1 = (const float*)d_in[4];
    const float* W2 = (const float*)d_in[5];
    const float* b2 = (const float*)d_in[6];
    float* out = (float*)d_out;

    // workspace layout (8B-aligned csr first):
    float* ws = (float*)d_ws;
    int2*  csr    = (int2*)ws;                                  // E int2   (25.6 MB)
    float* deg    = ws + 2 * (size_t)N_EDGES;                   // N
    float* dinv   = deg + N_NODES;                              // N
    int*   cnt    = (int*)(dinv + N_NODES);                     // N
    int*   base   = cnt + N_NODES;                              // N
    int*   cursor = base + N_NODES;                             // N
    int*   bsum   = cursor + N_NODES;                           // 512
    unsigned short* hpre = (unsigned short*)(bsum + 512);       // N*64 bf16 (12.8 MB)
    float* agg1   = (float*)(hpre + (size_t)N_NODES * D_HID);   // N*64     (25.6 MB)
    float* z      = agg1 + (size_t)N_NODES * D_HID;             // N*40     (16 MB)

    k_init  <<<SCAN_NB,          256, 0, stream>>>(deg, cnt);
    k_count <<<N_EDGES / 256,    256, 0, stream>>>(ei, ew, deg, cnt);
    k_scan1 <<<SCAN_NB,          256, 0, stream>>>(cnt, base, bsum);
    k_scan2 <<<1,                512, 0, stream>>>(bsum);
    k_scan3 <<<SCAN_NB,          256, 0, stream>>>(base, cursor, bsum, deg, dinv);
    k_fill  <<<N_EDGES / 256,    256, 0, stream>>>(ei, ew, dinv, cursor, csr);
    k_gemm1 <<<N_NODES / 16,     256, 0, stream>>>(x, W1, hpre);
    k_gather1<<<N_NODES / 4,     256, 0, stream>>>(base, cursor, csr, hpre, dinv, agg1);
    k_gemm2 <<<N_NODES * N_CLS / 256, 256, 0, stream>>>(agg1, b1, W2, z);
    k_gather2_lsm<<<N_NODES / 4, 256, 0, stream>>>(base, cursor, csr, z, dinv, b2, out);
}

// Round 3
// 1194.660 us; speedup vs baseline: 1.8608x; 1.3819x over previous
//
#include <hip/hip_runtime.h>
#include <math.h>

#define N_NODES 100000
#define N_EDGES 3200000
#define D_FEAT  512
#define D_HID   64
#define N_CLS   40
#define SCAN_NB ((N_NODES + 255) / 256)   /* 391 */
#define BK      128                       /* gemm1 K-chunk staged in LDS */

static __device__ __forceinline__ unsigned short f2bf(float f) {
    unsigned u = __float_as_uint(f);
    unsigned r = (u + 0x7FFFu + ((u >> 16) & 1u)) >> 16;   // RNE
    return (unsigned short)r;
}
static __device__ __forceinline__ float bf2f(unsigned short h) {
    return __uint_as_float(((unsigned)h) << 16);
}

// ---------------- degree + in-degree count ----------------

__global__ __launch_bounds__(256) void k_init(float* __restrict__ deg, int* __restrict__ cnt) {
    int n = blockIdx.x * 256 + threadIdx.x;
    if (n < N_NODES) { deg[n] = 1.0f; cnt[n] = 0; }   // self-loop weight 1
}

__global__ __launch_bounds__(256) void k_count(const int* __restrict__ ei,
                                               const float* __restrict__ ew,
                                               float* __restrict__ deg,
                                               int* __restrict__ cnt) {
    int e = blockIdx.x * 256 + threadIdx.x;
    int c = ei[N_EDGES + e];
    atomicAdd(&cnt[c], 1);
    unsafeAtomicAdd(&deg[c], ew[e]);
}

// ---------------- exclusive scan of cnt -> base ----------------

__global__ __launch_bounds__(256) void k_scan1(const int* __restrict__ cnt,
                                               int* __restrict__ base,
                                               int* __restrict__ bsum) {
    __shared__ int s[256];
    int tid = threadIdx.x;
    int i = blockIdx.x * 256 + tid;
    int v = (i < N_NODES) ? cnt[i] : 0;
    s[tid] = v;
    __syncthreads();
    for (int off = 1; off < 256; off <<= 1) {
        int t = (tid >= off) ? s[tid - off] : 0;
        __syncthreads();
        s[tid] += t;
        __syncthreads();
    }
    if (i < N_NODES) base[i] = s[tid] - v;      // exclusive
    if (tid == 255) bsum[blockIdx.x] = s[255];  // block total
}

__global__ __launch_bounds__(512) void k_scan2(int* __restrict__ bsum) {
    __shared__ int s[512];
    int tid = threadIdx.x;
    int v = (tid < SCAN_NB) ? bsum[tid] : 0;
    s[tid] = v;
    __syncthreads();
    for (int off = 1; off < 512; off <<= 1) {
        int t = (tid >= off) ? s[tid - off] : 0;
        __syncthreads();
        s[tid] += t;
        __syncthreads();
    }
    bsum[tid] = s[tid] - v;                     // exclusive block offsets
}

__global__ __launch_bounds__(256) void k_scan3(int* __restrict__ base,
                                               int* __restrict__ cursor,
                                               const int* __restrict__ bsum,
                                               const float* __restrict__ deg,
                                               float* __restrict__ dinv) {
    int i = blockIdx.x * 256 + threadIdx.x;
    if (i < N_NODES) {
        int b = base[i] + bsum[blockIdx.x];
        base[i] = b;
        cursor[i] = b;
        dinv[i] = rsqrtf(deg[i]);               // deg >= 1 always
    }
}

// ---------------- CSR fill: (src, norm) per incoming edge, bucketed by dst ----------------

__global__ __launch_bounds__(256) void k_fill(const int* __restrict__ ei,
                                              const float* __restrict__ ew,
                                              const float* __restrict__ dinv,
                                              int* __restrict__ cursor,
                                              int2* __restrict__ csr) {
    int e = blockIdx.x * 256 + threadIdx.x;
    int r = ei[e];
    int c = ei[N_EDGES + e];
    float nrm = dinv[r] * ew[e] * dinv[c];
    int slot = atomicAdd(&cursor[c], 1);
    csr[slot] = make_int2(r, __float_as_int(nrm));
}

// ---------------- layer 1 GEMM: hpre(bf16) = x @ W1 ----------------
// Block = 256 thr = 4 waves; block computes 16 rows x 64 cols. x-tile (16 x BK)
// staged in LDS via coalesced float4 coop-loads; compute reads it with
// wave-uniform ds_read_b128 broadcasts (free). W1 read coalesced from L1/L2.
// 6250 blocks.

__global__ __launch_bounds__(256) void k_gemm1(const float* __restrict__ x,
                                               const float* __restrict__ W1,
                                               unsigned short* __restrict__ hpre) {
    __shared__ float xs[16][BK];                 // 8 KB
    const int tid = threadIdx.x;
    const int col = tid & 63;
    const int rg  = tid >> 6;                    // wave 0..3 -> rows rg*4..rg*4+3
    const int r0  = blockIdx.x * 16;

    float a0 = 0.f, a1 = 0.f, a2 = 0.f, a3 = 0.f;

    for (int k0 = 0; k0 < D_FEAT; k0 += BK) {
        __syncthreads();
        // coop load 16 rows x BK floats = 512 float4, 2 per thread, coalesced
#pragma unroll
        for (int i = 0; i < 2; i++) {
            int idx = tid + i * 256;             // 0..511
            int r   = idx >> 5;                  // 32 float4 per row
            int kk  = (idx & 31) << 2;
            *(float4*)&xs[r][kk] =
                *(const float4*)&x[(size_t)(r0 + r) * D_FEAT + k0 + kk];
        }
        __syncthreads();

        const float* wp = W1 + (size_t)k0 * D_HID + col;
#pragma unroll 4
        for (int kq = 0; kq < BK; kq += 4) {
            float4 x0 = *(const float4*)&xs[rg * 4 + 0][kq];   // broadcast reads
            float4 x1 = *(const float4*)&xs[rg * 4 + 1][kq];
            float4 x2 = *(const float4*)&xs[rg * 4 + 2][kq];
            float4 x3 = *(const float4*)&xs[rg * 4 + 3][kq];
            float w0 = wp[(kq + 0) * D_HID];
            float w1 = wp[(kq + 1) * D_HID];
            float w2 = wp[(kq + 2) * D_HID];
            float w3 = wp[(kq + 3) * D_HID];
            a0 += x0.x * w0 + x0.y * w1 + x0.z * w2 + x0.w * w3;
            a1 += x1.x * w0 + x1.y * w1 + x1.z * w2 + x1.w * w3;
            a2 += x2.x * w0 + x2.y * w1 + x2.z * w2 + x2.w * w3;
            a3 += x3.x * w0 + x3.y * w1 + x3.z * w2 + x3.w * w3;
        }
    }

    const int r = r0 + rg * 4;
    hpre[(size_t)(r + 0) * D_HID + col] = f2bf(a0);
    hpre[(size_t)(r + 1) * D_HID + col] = f2bf(a1);
    hpre[(size_t)(r + 2) * D_HID + col] = f2bf(a2);
    hpre[(size_t)(r + 3) * D_HID + col] = f2bf(a3);
}

// ---------------- layer 1 gather: agg1[n] = d^2*hpre[n] + sum nrm*hpre[src] ----------------
// wave per node, lane = feature, 4-wide unroll for MLP. 25000 blocks.

__global__ __launch_bounds__(256) void k_gather1(const int* __restrict__ base,
                                                 const int* __restrict__ cursor,
                                                 const int2* __restrict__ csr,
                                                 const unsigned short* __restrict__ hpre,
                                                 const float* __restrict__ dinv,
                                                 float* __restrict__ agg1) {
    int lane = threadIdx.x & 63;
    int n = blockIdx.x * 4 + (threadIdx.x >> 6);
    int s = base[n], e = cursor[n];   // cursor == end after fill
    float d = dinv[n];
    float acc0 = d * d * bf2f(hpre[(size_t)n * D_HID + lane]);
    float acc1 = 0.f, acc2 = 0.f, acc3 = 0.f;
    int j = s;
    for (; j + 3 < e; j += 4) {
        int2 p0 = csr[j];
        int2 p1 = csr[j + 1];
        int2 p2 = csr[j + 2];
        int2 p3 = csr[j + 3];
        acc0 += __int_as_float(p0.y) * bf2f(hpre[(size_t)p0.x * D_HID + lane]);
        acc1 += __int_as_float(p1.y) * bf2f(hpre[(size_t)p1.x * D_HID + lane]);
        acc2 += __int_as_float(p2.y) * bf2f(hpre[(size_t)p2.x * D_HID + lane]);
        acc3 += __int_as_float(p3.y) * bf2f(hpre[(size_t)p3.x * D_HID + lane]);
    }
    for (; j < e; j++) {
        int2 p = csr[j];
        acc0 += __int_as_float(p.y) * bf2f(hpre[(size_t)p.x * D_HID + lane]);
    }
    agg1[(size_t)n * D_HID + lane] = (acc0 + acc1) + (acc2 + acc3);
}

// ---------------- layer 2 GEMM: z = relu(agg1 + b1) @ W2 ----------------
// thread per (node, class). 15625 blocks.

__global__ __launch_bounds__(256) void k_gemm2(const float* __restrict__ agg1,
                                               const float* __restrict__ b1,
                                               const float* __restrict__ W2,
                                               float* __restrict__ z) {
    int gid = blockIdx.x * 256 + threadIdx.x;
    int n = gid / N_CLS;
    int c = gid - n * N_CLS;
    const float* ap = agg1 + (size_t)n * D_HID;
    float acc = 0.f;
#pragma unroll 8
    for (int k = 0; k < D_HID; k++) {
        float h = ap[k] + b1[k];
        h = h > 0.f ? h : 0.f;
        acc += h * W2[k * N_CLS + c];
    }
    z[gid] = acc;
}

// ---------------- layer 2 gather + bias + log_softmax fused ----------------
// wave per node, lanes < 40 active, 4-wide unroll. 25000 blocks.

__global__ __launch_bounds__(256) void k_gather2_lsm(const int* __restrict__ base,
                                                     const int* __restrict__ cursor,
                                                     const int2* __restrict__ csr,
                                                     const float* __restrict__ z,
                                                     const float* __restrict__ dinv,
                                                     const float* __restrict__ b2,
                                                     float* __restrict__ out) {
    int lane = threadIdx.x & 63;
    int n = blockIdx.x * 4 + (threadIdx.x >> 6);
    bool act = lane < N_CLS;
    int fl = act ? lane : (N_CLS - 1);          // clamped lane for safe loads
    int s = base[n], e = cursor[n];
    float d = dinv[n];
    float acc0 = d * d * z[(size_t)n * N_CLS + fl];
    float acc1 = 0.f, acc2 = 0.f, acc3 = 0.f;
    int j = s;
    for (; j + 3 < e; j += 4) {
        int2 p0 = csr[j];
        int2 p1 = csr[j + 1];
        int2 p2 = csr[j + 2];
        int2 p3 = csr[j + 3];
        acc0 += __int_as_float(p0.y) * z[(size_t)p0.x * N_CLS + fl];
        acc1 += __int_as_float(p1.y) * z[(size_t)p1.x * N_CLS + fl];
        acc2 += __int_as_float(p2.y) * z[(size_t)p2.x * N_CLS + fl];
        acc3 += __int_as_float(p3.y) * z[(size_t)p3.x * N_CLS + fl];
    }
    for (; j < e; j++) {
        int2 p = csr[j];
        acc0 += __int_as_float(p.y) * z[(size_t)p.x * N_CLS + fl];
    }
    float logit = (acc0 + acc1) + (acc2 + acc3) + b2[fl];  // junk lanes >= 40 masked below
    float m = act ? logit : -INFINITY;
    for (int off = 32; off; off >>= 1) m = fmaxf(m, __shfl_xor(m, off, 64));
    float ev = act ? expf(logit - m) : 0.f;
    float sum = ev;
    for (int off = 32; off; off >>= 1) sum += __shfl_xor(sum, off, 64);
    if (act) out[(size_t)n * N_CLS + lane] = logit - m - logf(sum);
}

// ---------------- launch ----------------

extern "C" void kernel_launch(void* const* d_in, const int* in_sizes, int n_in,
                              void* d_out, int out_size, void* d_ws, size_t ws_size,
                              hipStream_t stream) {
    const float* x  = (const float*)d_in[0];
    const int*   ei = (const int*)d_in[1];
    const float* ew = (const float*)d_in[2];
    const float* W1 = (const float*)d_in[3];
    const float* b1 = (const float*)d_in[4];
    const float* W2 = (const float*)d_in[5];
    const float* b2 = (const float*)d_in[6];
    float* out = (float*)d_out;

    float* ws = (float*)d_ws;
    int2*  csr    = (int2*)ws;                                  // E int2   (25.6 MB)
    float* deg    = ws + 2 * (size_t)N_EDGES;                   // N
    float* dinv   = deg + N_NODES;                              // N
    int*   cnt    = (int*)(dinv + N_NODES);                     // N
    int*   base   = cnt + N_NODES;                              // N
    int*   cursor = base + N_NODES;                             // N
    int*   bsum   = cursor + N_NODES;                           // 512
    unsigned short* hpre = (unsigned short*)(bsum + 512);       // N*64 bf16 (12.8 MB)
    float* agg1   = (float*)(hpre + (size_t)N_NODES * D_HID);   // N*64     (25.6 MB)
    float* z      = agg1 + (size_t)N_NODES * D_HID;             // N*40     (16 MB)

    k_init  <<<SCAN_NB,          256, 0, stream>>>(deg, cnt);
    k_count <<<N_EDGES / 256,    256, 0, stream>>>(ei, ew, deg, cnt);
    k_scan1 <<<SCAN_NB,          256, 0, stream>>>(cnt, base, bsum);
    k_scan2 <<<1,                512, 0, stream>>>(bsum);
    k_scan3 <<<SCAN_NB,          256, 0, stream>>>(base, cursor, bsum, deg, dinv);
    k_fill  <<<N_EDGES / 256,    256, 0, stream>>>(ei, ew, dinv, cursor, csr);
    k_gemm1 <<<N_NODES / 16,     256, 0, stream>>>(x, W1, hpre);
    k_gather1<<<N_NODES / 4,     256, 0, stream>>>(base, cursor, csr, hpre, dinv, agg1);
    k_gemm2 <<<N_NODES * N_CLS / 256, 256, 0, stream>>>(agg1, b1, W2, z);
    k_gather2_lsm<<<N_NODES / 4, 256, 0, stream>>>(base, cursor, csr, z, dinv, b2, out);
}

// Round 4
// 1021.903 us; speedup vs baseline: 2.1754x; 1.1691x over previous
//
#include <hip/hip_runtime.h>
#include <math.h>

#define N_NODES 100000
#define N_EDGES 3200000
#define D_FEAT  512
#define D_HID   64
#define N_CLS   40
#define SCAN_NB ((N_NODES + 255) / 256)   /* 391 */
#define BK      128                       /* gemm1 K-chunk staged in LDS */

static __device__ __forceinline__ unsigned short f2bf(float f) {
    unsigned u = __float_as_uint(f);
    unsigned r = (u + 0x7FFFu + ((u >> 16) & 1u)) >> 16;   // RNE
    return (unsigned short)r;
}
static __device__ __forceinline__ float bf2f(unsigned short h) {
    return __uint_as_float(((unsigned)h) << 16);
}

// ---------------- init ----------------

__global__ __launch_bounds__(256) void k_init(int* __restrict__ cnt) {
    int n = blockIdx.x * 256 + threadIdx.x;
    if (n < N_NODES) cnt[n] = 0;
}

// ---------------- count: ONE atomic per edge, returning the slot sequence ----------------

__global__ __launch_bounds__(256) void k_count(const int* __restrict__ ei,
                                               int* __restrict__ cnt,
                                               int* __restrict__ seq) {
    int e = blockIdx.x * 256 + threadIdx.x;
    int c = ei[N_EDGES + e];
    seq[e] = atomicAdd(&cnt[c], 1);
}

// ---------------- exclusive scan of cnt -> base ----------------

__global__ __launch_bounds__(256) void k_scan1(const int* __restrict__ cnt,
                                               int* __restrict__ base,
                                               int* __restrict__ bsum) {
    __shared__ int s[256];
    int tid = threadIdx.x;
    int i = blockIdx.x * 256 + tid;
    int v = (i < N_NODES) ? cnt[i] : 0;
    s[tid] = v;
    __syncthreads();
    for (int off = 1; off < 256; off <<= 1) {
        int t = (tid >= off) ? s[tid - off] : 0;
        __syncthreads();
        s[tid] += t;
        __syncthreads();
    }
    if (i < N_NODES) base[i] = s[tid] - v;      // exclusive
    if (tid == 255) bsum[blockIdx.x] = s[255];  // block total
}

__global__ __launch_bounds__(512) void k_scan2(int* __restrict__ bsum) {
    __shared__ int s[512];
    int tid = threadIdx.x;
    int v = (tid < SCAN_NB) ? bsum[tid] : 0;
    s[tid] = v;
    __syncthreads();
    for (int off = 1; off < 512; off <<= 1) {
        int t = (tid >= off) ? s[tid - off] : 0;
        __syncthreads();
        s[tid] += t;
        __syncthreads();
    }
    bsum[tid] = s[tid] - v;                     // exclusive block offsets
}

__global__ __launch_bounds__(256) void k_scan3(int* __restrict__ base,
                                               const int* __restrict__ bsum) {
    int i = blockIdx.x * 256 + threadIdx.x;
    if (i < N_NODES) base[i] += bsum[blockIdx.x];
}

// ---------------- CSR fill: NO atomics; slot = base[dst] + seq[e] ----------------

__global__ __launch_bounds__(256) void k_fill(const int* __restrict__ ei,
                                              const float* __restrict__ ew,
                                              const int* __restrict__ base,
                                              const int* __restrict__ seq,
                                              int2* __restrict__ csr) {
    int e = blockIdx.x * 256 + threadIdx.x;
    int r = ei[e];
    int c = ei[N_EDGES + e];
    int slot = base[c] + seq[e];
    csr[slot] = make_int2(r, __float_as_int(ew[e]));
}

// ---------------- deg from CSR buckets: dinv[n] = rsqrt(1 + sum ew) ----------------
// wave per node, lanes stride the bucket. 25000 blocks.

__global__ __launch_bounds__(256) void k_deg(const int* __restrict__ base,
                                             const int* __restrict__ cnt,
                                             const int2* __restrict__ csr,
                                             float* __restrict__ dinv) {
    int lane = threadIdx.x & 63;
    int n = blockIdx.x * 4 + (threadIdx.x >> 6);
    int s = base[n], e = s + cnt[n];
    float sum = 0.f;
    for (int j = s + lane; j < e; j += 64)
        sum += __int_as_float(csr[j].y);
    for (int off = 32; off; off >>= 1) sum += __shfl_xor(sum, off, 64);
    if (lane == 0) dinv[n] = rsqrtf(1.0f + sum);   // self-loop weight 1
}

// ---------------- layer 1 GEMM: hpre(bf16) = x @ W1 ----------------
// Block = 4 waves; block computes 16 rows x 64 cols; x-tile staged in LDS. 6250 blocks.

__global__ __launch_bounds__(256) void k_gemm1(const float* __restrict__ x,
                                               const float* __restrict__ W1,
                                               unsigned short* __restrict__ hpre) {
    __shared__ float xs[16][BK];                 // 8 KB
    const int tid = threadIdx.x;
    const int col = tid & 63;
    const int rg  = tid >> 6;                    // wave 0..3 -> rows rg*4..rg*4+3
    const int r0  = blockIdx.x * 16;

    float a0 = 0.f, a1 = 0.f, a2 = 0.f, a3 = 0.f;

    for (int k0 = 0; k0 < D_FEAT; k0 += BK) {
        __syncthreads();
#pragma unroll
        for (int i = 0; i < 2; i++) {
            int idx = tid + i * 256;             // 0..511
            int r   = idx >> 5;                  // 32 float4 per row
            int kk  = (idx & 31) << 2;
            *(float4*)&xs[r][kk] =
                *(const float4*)&x[(size_t)(r0 + r) * D_FEAT + k0 + kk];
        }
        __syncthreads();

        const float* wp = W1 + (size_t)k0 * D_HID + col;
#pragma unroll 4
        for (int kq = 0; kq < BK; kq += 4) {
            float4 x0 = *(const float4*)&xs[rg * 4 + 0][kq];   // broadcast reads
            float4 x1 = *(const float4*)&xs[rg * 4 + 1][kq];
            float4 x2 = *(const float4*)&xs[rg * 4 + 2][kq];
            float4 x3 = *(const float4*)&xs[rg * 4 + 3][kq];
            float w0 = wp[(kq + 0) * D_HID];
            float w1 = wp[(kq + 1) * D_HID];
            float w2 = wp[(kq + 2) * D_HID];
            float w3 = wp[(kq + 3) * D_HID];
            a0 += x0.x * w0 + x0.y * w1 + x0.z * w2 + x0.w * w3;
            a1 += x1.x * w0 + x1.y * w1 + x1.z * w2 + x1.w * w3;
            a2 += x2.x * w0 + x2.y * w1 + x2.z * w2 + x2.w * w3;
            a3 += x3.x * w0 + x3.y * w1 + x3.z * w2 + x3.w * w3;
        }
    }

    const int r = r0 + rg * 4;
    hpre[(size_t)(r + 0) * D_HID + col] = f2bf(a0);
    hpre[(size_t)(r + 1) * D_HID + col] = f2bf(a1);
    hpre[(size_t)(r + 2) * D_HID + col] = f2bf(a2);
    hpre[(size_t)(r + 3) * D_HID + col] = f2bf(a3);
}

// ---------------- layer 1 gather: agg1[n] = d^2*hpre[n] + sum nrm*hpre[src] ----------------
// wave per node, lane = feature, nrm computed on the fly. 25000 blocks.

__global__ __launch_bounds__(256) void k_gather1(const int* __restrict__ base,
                                                 const int* __restrict__ cnt,
                                                 const int2* __restrict__ csr,
                                                 const unsigned short* __restrict__ hpre,
                                                 const float* __restrict__ dinv,
                                                 float* __restrict__ agg1) {
    int lane = threadIdx.x & 63;
    int n = blockIdx.x * 4 + (threadIdx.x >> 6);
    int s = base[n], e = s + cnt[n];
    float dn = dinv[n];
    float acc0 = dn * dn * bf2f(hpre[(size_t)n * D_HID + lane]);
    float acc1 = 0.f, acc2 = 0.f, acc3 = 0.f;
    int j = s;
    for (; j + 3 < e; j += 4) {
        int2 p0 = csr[j];
        int2 p1 = csr[j + 1];
        int2 p2 = csr[j + 2];
        int2 p3 = csr[j + 3];
        float n0 = dinv[p0.x] * __int_as_float(p0.y) * dn;
        float n1 = dinv[p1.x] * __int_as_float(p1.y) * dn;
        float n2 = dinv[p2.x] * __int_as_float(p2.y) * dn;
        float n3 = dinv[p3.x] * __int_as_float(p3.y) * dn;
        acc0 += n0 * bf2f(hpre[(size_t)p0.x * D_HID + lane]);
        acc1 += n1 * bf2f(hpre[(size_t)p1.x * D_HID + lane]);
        acc2 += n2 * bf2f(hpre[(size_t)p2.x * D_HID + lane]);
        acc3 += n3 * bf2f(hpre[(size_t)p3.x * D_HID + lane]);
    }
    for (; j < e; j++) {
        int2 p = csr[j];
        acc0 += dinv[p.x] * __int_as_float(p.y) * dn * bf2f(hpre[(size_t)p.x * D_HID + lane]);
    }
    agg1[(size_t)n * D_HID + lane] = (acc0 + acc1) + (acc2 + acc3);
}

// ---------------- layer 2 GEMM: z = relu(agg1 + b1) @ W2 ----------------

__global__ __launch_bounds__(256) void k_gemm2(const float* __restrict__ agg1,
                                               const float* __restrict__ b1,
                                               const float* __restrict__ W2,
                                               float* __restrict__ z) {
    int gid = blockIdx.x * 256 + threadIdx.x;
    int n = gid / N_CLS;
    int c = gid - n * N_CLS;
    const float* ap = agg1 + (size_t)n * D_HID;
    float acc = 0.f;
#pragma unroll 8
    for (int k = 0; k < D_HID; k++) {
        float h = ap[k] + b1[k];
        h = h > 0.f ? h : 0.f;
        acc += h * W2[k * N_CLS + c];
    }
    z[gid] = acc;
}

// ---------------- layer 2 gather + bias + log_softmax fused ----------------

__global__ __launch_bounds__(256) void k_gather2_lsm(const int* __restrict__ base,
                                                     const int* __restrict__ cnt,
                                                     const int2* __restrict__ csr,
                                                     const float* __restrict__ z,
                                                     const float* __restrict__ dinv,
                                                     const float* __restrict__ b2,
                                                     float* __restrict__ out) {
    int lane = threadIdx.x & 63;
    int n = blockIdx.x * 4 + (threadIdx.x >> 6);
    bool act = lane < N_CLS;
    int fl = act ? lane : (N_CLS - 1);          // clamped lane for safe loads
    int s = base[n], e = s + cnt[n];
    float dn = dinv[n];
    float acc0 = dn * dn * z[(size_t)n * N_CLS + fl];
    float acc1 = 0.f, acc2 = 0.f, acc3 = 0.f;
    int j = s;
    for (; j + 3 < e; j += 4) {
        int2 p0 = csr[j];
        int2 p1 = csr[j + 1];
        int2 p2 = csr[j + 2];
        int2 p3 = csr[j + 3];
        float n0 = dinv[p0.x] * __int_as_float(p0.y) * dn;
        float n1 = dinv[p1.x] * __int_as_float(p1.y) * dn;
        float n2 = dinv[p2.x] * __int_as_float(p2.y) * dn;
        float n3 = dinv[p3.x] * __int_as_float(p3.y) * dn;
        acc0 += n0 * z[(size_t)p0.x * N_CLS + fl];
        acc1 += n1 * z[(size_t)p1.x * N_CLS + fl];
        acc2 += n2 * z[(size_t)p2.x * N_CLS + fl];
        acc3 += n3 * z[(size_t)p3.x * N_CLS + fl];
    }
    for (; j < e; j++) {
        int2 p = csr[j];
        acc0 += dinv[p.x] * __int_as_float(p.y) * dn * z[(size_t)p.x * N_CLS + fl];
    }
    float logit = (acc0 + acc1) + (acc2 + acc3) + b2[fl];  // junk lanes >= 40 masked below
    float m = act ? logit : -INFINITY;
    for (int off = 32; off; off >>= 1) m = fmaxf(m, __shfl_xor(m, off, 64));
    float ev = act ? expf(logit - m) : 0.f;
    float sum = ev;
    for (int off = 32; off; off >>= 1) sum += __shfl_xor(sum, off, 64);
    if (act) out[(size_t)n * N_CLS + lane] = logit - m - logf(sum);
}

// ---------------- launch ----------------

extern "C" void kernel_launch(void* const* d_in, const int* in_sizes, int n_in,
                              void* d_out, int out_size, void* d_ws, size_t ws_size,
                              hipStream_t stream) {
    const float* x  = (const float*)d_in[0];
    const int*   ei = (const int*)d_in[1];
    const float* ew = (const float*)d_in[2];
    const float* W1 = (const float*)d_in[3];
    const float* b1 = (const float*)d_in[4];
    const float* W2 = (const float*)d_in[5];
    const float* b2 = (const float*)d_in[6];
    float* out = (float*)d_out;

    // workspace layout:
    //   csr  : E int2      25.6 MB
    //   seq  : E int       12.8 MB  -- dead after k_fill; hpre aliases it
    //   cnt, base, bsum, dinv : small
    //   agg1 : N*64 f32    25.6 MB
    //   z    : N*40 f32    16 MB
    float* ws = (float*)d_ws;
    int2*  csr  = (int2*)ws;
    int*   seq  = (int*)(ws + 2 * (size_t)N_EDGES);
    int*   cnt  = seq + N_EDGES;
    int*   base = cnt + N_NODES;
    int*   bsum = base + N_NODES;
    float* dinv = (float*)(bsum + 512);
    unsigned short* hpre = (unsigned short*)seq;               // alias (seq dead post-fill)
    float* agg1 = dinv + N_NODES;
    float* z    = agg1 + (size_t)N_NODES * D_HID;

    k_init  <<<SCAN_NB,          256, 0, stream>>>(cnt);
    k_count <<<N_EDGES / 256,    256, 0, stream>>>(ei, cnt, seq);
    k_scan1 <<<SCAN_NB,          256, 0, stream>>>(cnt, base, bsum);
    k_scan2 <<<1,                512, 0, stream>>>(bsum);
    k_scan3 <<<SCAN_NB,          256, 0, stream>>>(base, bsum);
    k_fill  <<<N_EDGES / 256,    256, 0, stream>>>(ei, ew, base, seq, csr);
    k_deg   <<<N_NODES / 4,      256, 0, stream>>>(base, cnt, csr, dinv);
    k_gemm1 <<<N_NODES / 16,     256, 0, stream>>>(x, W1, hpre);
    k_gather1<<<N_NODES / 4,     256, 0, stream>>>(base, cnt, csr, hpre, dinv, agg1);
    k_gemm2 <<<N_NODES * N_CLS / 256, 256, 0, stream>>>(agg1, b1, W2, z);
    k_gather2_lsm<<<N_NODES / 4, 256, 0, stream>>>(base, cnt, csr, z, dinv, b2, out);
}

// Round 5
// 875.447 us; speedup vs baseline: 2.5393x; 1.1673x over previous
//
#include <hip/hip_runtime.h>
#include <math.h>

#define N_NODES 100000
#define N_EDGES 3200000
#define D_FEAT  512
#define D_HID   64
#define N_CLS   40
#define SCAN_NB ((N_NODES + 255) / 256)   /* 391 */

typedef __attribute__((ext_vector_type(8))) short short8;
typedef __attribute__((ext_vector_type(4))) float floatx4;

static __device__ __forceinline__ unsigned short f2bf(float f) {
    unsigned u = __float_as_uint(f);
    unsigned r = (u + 0x7FFFu + ((u >> 16) & 1u)) >> 16;   // RNE
    return (unsigned short)r;
}
static __device__ __forceinline__ float bf2f(unsigned short h) {
    return __uint_as_float(((unsigned)h) << 16);
}
static __device__ __forceinline__ short8 pack_bf16x8(float4 a, float4 b) {
    short8 r;
    r[0] = (short)f2bf(a.x); r[1] = (short)f2bf(a.y);
    r[2] = (short)f2bf(a.z); r[3] = (short)f2bf(a.w);
    r[4] = (short)f2bf(b.x); r[5] = (short)f2bf(b.y);
    r[6] = (short)f2bf(b.z); r[7] = (short)f2bf(b.w);
    return r;
}

// ---------------- init ----------------

__global__ __launch_bounds__(256) void k_init(int* __restrict__ cnt) {
    int n = blockIdx.x * 256 + threadIdx.x;
    if (n < N_NODES) cnt[n] = 0;
}

// ---------------- count: ONE atomic per edge, returning the slot sequence ----------------

__global__ __launch_bounds__(256) void k_count(const int* __restrict__ ei,
                                               int* __restrict__ cnt,
                                               int* __restrict__ seq) {
    int e = blockIdx.x * 256 + threadIdx.x;
    int c = ei[N_EDGES + e];
    seq[e] = atomicAdd(&cnt[c], 1);
}

// ---------------- exclusive scan of cnt -> base ----------------

__global__ __launch_bounds__(256) void k_scan1(const int* __restrict__ cnt,
                                               int* __restrict__ base,
                                               int* __restrict__ bsum) {
    __shared__ int s[256];
    int tid = threadIdx.x;
    int i = blockIdx.x * 256 + tid;
    int v = (i < N_NODES) ? cnt[i] : 0;
    s[tid] = v;
    __syncthreads();
    for (int off = 1; off < 256; off <<= 1) {
        int t = (tid >= off) ? s[tid - off] : 0;
        __syncthreads();
        s[tid] += t;
        __syncthreads();
    }
    if (i < N_NODES) base[i] = s[tid] - v;      // exclusive
    if (tid == 255) bsum[blockIdx.x] = s[255];  // block total
}

__global__ __launch_bounds__(512) void k_scan2(int* __restrict__ bsum) {
    __shared__ int s[512];
    int tid = threadIdx.x;
    int v = (tid < SCAN_NB) ? bsum[tid] : 0;
    s[tid] = v;
    __syncthreads();
    for (int off = 1; off < 512; off <<= 1) {
        int t = (tid >= off) ? s[tid - off] : 0;
        __syncthreads();
        s[tid] += t;
        __syncthreads();
    }
    bsum[tid] = s[tid] - v;                     // exclusive block offsets
}

__global__ __launch_bounds__(256) void k_scan3(int* __restrict__ base,
                                               const int* __restrict__ bsum) {
    int i = blockIdx.x * 256 + threadIdx.x;
    if (i < N_NODES) base[i] += bsum[blockIdx.x];
}

// ---------------- CSR fill: NO atomics; slot = base[dst] + seq[e] ----------------

__global__ __launch_bounds__(256) void k_fill(const int* __restrict__ ei,
                                              const float* __restrict__ ew,
                                              const int* __restrict__ base,
                                              const int* __restrict__ seq,
                                              int2* __restrict__ csr) {
    int e = blockIdx.x * 256 + threadIdx.x;
    int r = ei[e];
    int c = ei[N_EDGES + e];
    int slot = base[c] + seq[e];
    csr[slot] = make_int2(r, __float_as_int(ew[e]));
}

// ---------------- deg from CSR buckets: dinv[n] = rsqrt(1 + sum ew) ----------------

__global__ __launch_bounds__(256) void k_deg(const int* __restrict__ base,
                                             const int* __restrict__ cnt,
                                             const int2* __restrict__ csr,
                                             float* __restrict__ dinv) {
    int lane = threadIdx.x & 63;
    int n = blockIdx.x * 4 + (threadIdx.x >> 6);
    int s = base[n], e = s + cnt[n];
    float sum = 0.f;
    for (int j = s + lane; j < e; j += 64)
        sum += __int_as_float(csr[j].y);
    for (int off = 32; off; off >>= 1) sum += __shfl_xor(sum, off, 64);
    if (lane == 0) dinv[n] = rsqrtf(1.0f + sum);   // self-loop weight 1
}

// ---------------- layer 1 GEMM via MFMA: hpre(bf16) = x @ W1 ----------------
// Block = 4 waves; each wave = 16 rows x 64 cols, K=512 (16 mfma_16x16x32 steps x 4 col-tiles).
// W1^T staged bf16 in LDS (64 KB exactly), k-block XOR swizzle kills bank conflicts.
// A-frags loaded from global in MFMA layout (A[m=lane&15][k=quad*8+j]), cvt to bf16 in-reg.
// 1563 blocks (6250 waves; last 2 waves idle).

__global__ __launch_bounds__(256) void k_gemm1(const float* __restrict__ x,
                                               const float* __restrict__ W1,
                                               unsigned short* __restrict__ hpre) {
    __shared__ __align__(16) short Wt[64 * 512];   // 65536 B
    const int tid = threadIdx.x;

    // ---- stage W1^T (bf16), coalesced reads, b128 swizzled writes ----
    {
        const int c  = tid & 63;
        const int kb = (tid >> 6) * 128;
        const int sw = (c & 7) << 3;
        for (int kk = 0; kk < 128; kk += 8) {
            short8 v;
#pragma unroll
            for (int j = 0; j < 8; j++)
                v[j] = (short)f2bf(W1[(size_t)(kb + kk + j) * D_HID + c]);
            *(short8*)&Wt[c * 512 + ((kb + kk) ^ sw)] = v;
        }
    }
    __syncthreads();

    const int widx = blockIdx.x * 4 + (tid >> 6);
    if (widx >= N_NODES / 16) return;
    const int lane = tid & 63;
    const int q  = lane >> 4;
    const int cn = lane & 15;
    const int r0 = widx * 16;
    const int sw = (cn & 7) << 3;

    floatx4 acc[4] = {{0,0,0,0},{0,0,0,0},{0,0,0,0},{0,0,0,0}};
    const float* xp = x + (size_t)(r0 + cn) * D_FEAT + q * 8;

#pragma unroll 4
    for (int k0 = 0; k0 < D_FEAT; k0 += 32) {
        float4 xa = *(const float4*)(xp + k0);
        float4 xb = *(const float4*)(xp + k0 + 4);
        short8 a = pack_bf16x8(xa, xb);
#pragma unroll
        for (int ct = 0; ct < 4; ct++) {
            short8 b = *(const short8*)&Wt[(ct * 16 + cn) * 512 + ((k0 + q * 8) ^ sw)];
            acc[ct] = __builtin_amdgcn_mfma_f32_16x16x32_bf16(a, b, acc[ct], 0, 0, 0);
        }
    }

    // C/D: col = lane&15 (cn), row = q*4 + reg  [m89/m91]
#pragma unroll
    for (int ct = 0; ct < 4; ct++)
#pragma unroll
        for (int i = 0; i < 4; i++)
            hpre[(size_t)(r0 + q * 4 + i) * D_HID + ct * 16 + cn] = f2bf(acc[ct][i]);
}

// ---------------- layer 1 gather: agg1[n] = dn*(dn*h[n] + sum (dinv_src*ew)*h[src]) ----------------
// wave per node, lane = feature, 8-deep MLP. 25000 blocks.

__global__ __launch_bounds__(256) void k_gather1(const int* __restrict__ base,
                                                 const int* __restrict__ cnt,
                                                 const int2* __restrict__ csr,
                                                 const unsigned short* __restrict__ hpre,
                                                 const float* __restrict__ dinv,
                                                 float* __restrict__ agg1) {
    int lane = threadIdx.x & 63;
    int n = blockIdx.x * 4 + (threadIdx.x >> 6);
    int s = base[n], e = s + cnt[n];
    float dn = dinv[n];
    float a0 = dn * bf2f(hpre[(size_t)n * D_HID + lane]);
    float a1 = 0.f, a2 = 0.f, a3 = 0.f, a4 = 0.f, a5 = 0.f, a6 = 0.f, a7 = 0.f;
    int j = s;
    for (; j + 7 < e; j += 8) {
        int2 p0 = csr[j];     int2 p1 = csr[j + 1];
        int2 p2 = csr[j + 2]; int2 p3 = csr[j + 3];
        int2 p4 = csr[j + 4]; int2 p5 = csr[j + 5];
        int2 p6 = csr[j + 6]; int2 p7 = csr[j + 7];
        float w0 = dinv[p0.x] * __int_as_float(p0.y);
        float w1 = dinv[p1.x] * __int_as_float(p1.y);
        float w2 = dinv[p2.x] * __int_as_float(p2.y);
        float w3 = dinv[p3.x] * __int_as_float(p3.y);
        float w4 = dinv[p4.x] * __int_as_float(p4.y);
        float w5 = dinv[p5.x] * __int_as_float(p5.y);
        float w6 = dinv[p6.x] * __int_as_float(p6.y);
        float w7 = dinv[p7.x] * __int_as_float(p7.y);
        a0 += w0 * bf2f(hpre[(size_t)p0.x * D_HID + lane]);
        a1 += w1 * bf2f(hpre[(size_t)p1.x * D_HID + lane]);
        a2 += w2 * bf2f(hpre[(size_t)p2.x * D_HID + lane]);
        a3 += w3 * bf2f(hpre[(size_t)p3.x * D_HID + lane]);
        a4 += w4 * bf2f(hpre[(size_t)p4.x * D_HID + lane]);
        a5 += w5 * bf2f(hpre[(size_t)p5.x * D_HID + lane]);
        a6 += w6 * bf2f(hpre[(size_t)p6.x * D_HID + lane]);
        a7 += w7 * bf2f(hpre[(size_t)p7.x * D_HID + lane]);
    }
    for (; j + 3 < e; j += 4) {
        int2 p0 = csr[j];     int2 p1 = csr[j + 1];
        int2 p2 = csr[j + 2]; int2 p3 = csr[j + 3];
        float w0 = dinv[p0.x] * __int_as_float(p0.y);
        float w1 = dinv[p1.x] * __int_as_float(p1.y);
        float w2 = dinv[p2.x] * __int_as_float(p2.y);
        float w3 = dinv[p3.x] * __int_as_float(p3.y);
        a0 += w0 * bf2f(hpre[(size_t)p0.x * D_HID + lane]);
        a1 += w1 * bf2f(hpre[(size_t)p1.x * D_HID + lane]);
        a2 += w2 * bf2f(hpre[(size_t)p2.x * D_HID + lane]);
        a3 += w3 * bf2f(hpre[(size_t)p3.x * D_HID + lane]);
    }
    for (; j < e; j++) {
        int2 p = csr[j];
        a0 += dinv[p.x] * __int_as_float(p.y) * bf2f(hpre[(size_t)p.x * D_HID + lane]);
    }
    agg1[(size_t)n * D_HID + lane] = dn * (((a0 + a1) + (a2 + a3)) + ((a4 + a5) + (a6 + a7)));
}

// ---------------- layer 2 GEMM: z = relu(agg1 + b1) @ W2 ----------------

__global__ __launch_bounds__(256) void k_gemm2(const float* __restrict__ agg1,
                                               const float* __restrict__ b1,
                                               const float* __restrict__ W2,
                                               float* __restrict__ z) {
    int gid = blockIdx.x * 256 + threadIdx.x;
    int n = gid / N_CLS;
    int c = gid - n * N_CLS;
    const float* ap = agg1 + (size_t)n * D_HID;
    float acc = 0.f;
#pragma unroll 8
    for (int k = 0; k < D_HID; k++) {
        float h = ap[k] + b1[k];
        h = h > 0.f ? h : 0.f;
        acc += h * W2[k * N_CLS + c];
    }
    z[gid] = acc;
}

// ---------------- layer 2 gather + bias + log_softmax fused, 8-deep MLP ----------------

__global__ __launch_bounds__(256) void k_gather2_lsm(const int* __restrict__ base,
                                                     const int* __restrict__ cnt,
                                                     const int2* __restrict__ csr,
                                                     const float* __restrict__ z,
                                                     const float* __restrict__ dinv,
                                                     const float* __restrict__ b2,
                                                     float* __restrict__ out) {
    int lane = threadIdx.x & 63;
    int n = blockIdx.x * 4 + (threadIdx.x >> 6);
    bool act = lane < N_CLS;
    int fl = act ? lane : (N_CLS - 1);          // clamped lane for safe loads
    int s = base[n], e = s + cnt[n];
    float dn = dinv[n];
    float a0 = dn * z[(size_t)n * N_CLS + fl];
    float a1 = 0.f, a2 = 0.f, a3 = 0.f, a4 = 0.f, a5 = 0.f, a6 = 0.f, a7 = 0.f;
    int j = s;
    for (; j + 7 < e; j += 8) {
        int2 p0 = csr[j];     int2 p1 = csr[j + 1];
        int2 p2 = csr[j + 2]; int2 p3 = csr[j + 3];
        int2 p4 = csr[j + 4]; int2 p5 = csr[j + 5];
        int2 p6 = csr[j + 6]; int2 p7 = csr[j + 7];
        float w0 = dinv[p0.x] * __int_as_float(p0.y);
        float w1 = dinv[p1.x] * __int_as_float(p1.y);
        float w2 = dinv[p2.x] * __int_as_float(p2.y);
        float w3 = dinv[p3.x] * __int_as_float(p3.y);
        float w4 = dinv[p4.x] * __int_as_float(p4.y);
        float w5 = dinv[p5.x] * __int_as_float(p5.y);
        float w6 = dinv[p6.x] * __int_as_float(p6.y);
        float w7 = dinv[p7.x] * __int_as_float(p7.y);
        a0 += w0 * z[(size_t)p0.x * N_CLS + fl];
        a1 += w1 * z[(size_t)p1.x * N_CLS + fl];
        a2 += w2 * z[(size_t)p2.x * N_CLS + fl];
        a3 += w3 * z[(size_t)p3.x * N_CLS + fl];
        a4 += w4 * z[(size_t)p4.x * N_CLS + fl];
        a5 += w5 * z[(size_t)p5.x * N_CLS + fl];
        a6 += w6 * z[(size_t)p6.x * N_CLS + fl];
        a7 += w7 * z[(size_t)p7.x * N_CLS + fl];
    }
    for (; j + 3 < e; j += 4) {
        int2 p0 = csr[j];     int2 p1 = csr[j + 1];
        int2 p2 = csr[j + 2]; int2 p3 = csr[j + 3];
        float w0 = dinv[p0.x] * __int_as_float(p0.y);
        float w1 = dinv[p1.x] * __int_as_float(p1.y);
        float w2 = dinv[p2.x] * __int_as_float(p2.y);
        float w3 = dinv[p3.x] * __int_as_float(p3.y);
        a0 += w0 * z[(size_t)p0.x * N_CLS + fl];
        a1 += w1 * z[(size_t)p1.x * N_CLS + fl];
        a2 += w2 * z[(size_t)p2.x * N_CLS + fl];
        a3 += w3 * z[(size_t)p3.x * N_CLS + fl];
    }
    for (; j < e; j++) {
        int2 p = csr[j];
        a0 += dinv[p.x] * __int_as_float(p.y) * z[(size_t)p.x * N_CLS + fl];
    }
    float logit = dn * (((a0 + a1) + (a2 + a3)) + ((a4 + a5) + (a6 + a7))) + b2[fl];
    float m = act ? logit : -INFINITY;
    for (int off = 32; off; off >>= 1) m = fmaxf(m, __shfl_xor(m, off, 64));
    float ev = act ? expf(logit - m) : 0.f;
    float sum = ev;
    for (int off = 32; off; off >>= 1) sum += __shfl_xor(sum, off, 64);
    if (act) out[(size_t)n * N_CLS + lane] = logit - m - logf(sum);
}

// ---------------- launch ----------------

extern "C" void kernel_launch(void* const* d_in, const int* in_sizes, int n_in,
                              void* d_out, int out_size, void* d_ws, size_t ws_size,
                              hipStream_t stream) {
    const float* x  = (const float*)d_in[0];
    const int*   ei = (const int*)d_in[1];
    const float* ew = (const float*)d_in[2];
    const float* W1 = (const float*)d_in[3];
    const float* b1 = (const float*)d_in[4];
    const float* W2 = (const float*)d_in[5];
    const float* b2 = (const float*)d_in[6];
    float* out = (float*)d_out;

    float* ws = (float*)d_ws;
    int2*  csr  = (int2*)ws;                                   // E int2   25.6 MB
    int*   seq  = (int*)(ws + 2 * (size_t)N_EDGES);            // E int    12.8 MB (hpre aliases)
    int*   cnt  = seq + N_EDGES;
    int*   base = cnt + N_NODES;
    int*   bsum = base + N_NODES;
    float* dinv = (float*)(bsum + 512);
    unsigned short* hpre = (unsigned short*)seq;               // alias: seq dead after k_fill
    float* agg1 = dinv + N_NODES;                              // N*64 f32 25.6 MB
    float* z    = agg1 + (size_t)N_NODES * D_HID;              // N*40 f32 16 MB

    k_init  <<<SCAN_NB,          256, 0, stream>>>(cnt);
    k_count <<<N_EDGES / 256,    256, 0, stream>>>(ei, cnt, seq);
    k_scan1 <<<SCAN_NB,          256, 0, stream>>>(cnt, base, bsum);
    k_scan2 <<<1,                512, 0, stream>>>(bsum);
    k_scan3 <<<SCAN_NB,          256, 0, stream>>>(base, bsum);
    k_fill  <<<N_EDGES / 256,    256, 0, stream>>>(ei, ew, base, seq, csr);
    k_deg   <<<N_NODES / 4,      256, 0, stream>>>(base, cnt, csr, dinv);
    k_gemm1 <<<(N_NODES / 16 + 3) / 4, 256, 0, stream>>>(x, W1, hpre);
    k_gather1<<<N_NODES / 4,     256, 0, stream>>>(base, cnt, csr, hpre, dinv, agg1);
    k_gemm2 <<<N_NODES * N_CLS / 256, 256, 0, stream>>>(agg1, b1, W2, z);
    k_gather2_lsm<<<N_NODES / 4, 256, 0, stream>>>(base, cnt, csr, z, dinv, b2, out);
}

// Round 6
// 818.648 us; speedup vs baseline: 2.7155x; 1.0694x over previous
//
#include <hip/hip_runtime.h>
#include <math.h>

#define N_NODES 100000
#define N_EDGES 3200000
#define D_FEAT  512
#define D_HID   64
#define N_CLS   40
#define NBKT    391            /* coarse buckets = ceil(N/256), bucket = dst >> 8 */
#define NBLKA   256            /* blocks in passes A/B */
#define EPB     (N_EDGES / NBLKA)   /* 12500 edges per block */

typedef __attribute__((ext_vector_type(8))) short short8;
typedef __attribute__((ext_vector_type(4))) float floatx4;

static __device__ __forceinline__ unsigned short f2bf(float f) {
    unsigned u = __float_as_uint(f);
    unsigned r = (u + 0x7FFFu + ((u >> 16) & 1u)) >> 16;   // RNE
    return (unsigned short)r;
}
static __device__ __forceinline__ float bf2f(unsigned short h) {
    return __uint_as_float(((unsigned)h) << 16);
}
static __device__ __forceinline__ short8 pack_bf16x8(float4 a, float4 b) {
    short8 r;
    r[0] = (short)f2bf(a.x); r[1] = (short)f2bf(a.y);
    r[2] = (short)f2bf(a.z); r[3] = (short)f2bf(a.w);
    r[4] = (short)f2bf(b.x); r[5] = (short)f2bf(b.y);
    r[6] = (short)f2bf(b.z); r[7] = (short)f2bf(b.w);
    return r;
}

// ---------------- pass A: per-block coarse histogram (no global atomics) ----------------

__global__ __launch_bounds__(256) void k_histA(const int* __restrict__ ei,
                                               int* __restrict__ mat) {
    __shared__ int hist[NBKT];
    const int tid = threadIdx.x, blk = blockIdx.x;
    for (int i = tid; i < NBKT; i += 256) hist[i] = 0;
    __syncthreads();
    const int e0 = blk * EPB, e1 = e0 + EPB;
    for (int e = e0 + tid; e < e1; e += 256)
        atomicAdd(&hist[ei[N_EDGES + e] >> 8], 1);
    __syncthreads();
    for (int i = tid; i < NBKT; i += 256) mat[i * NBLKA + blk] = hist[i];
}

// ---------------- S1: per-bucket exclusive scan across blocks + row totals ----------------

__global__ __launch_bounds__(256) void k_scanRows(int* __restrict__ mat,
                                                  int* __restrict__ total) {
    __shared__ int s[256];
    const int tid = threadIdx.x, bin = blockIdx.x;
    int v = mat[bin * NBLKA + tid];
    s[tid] = v;
    __syncthreads();
    for (int off = 1; off < 256; off <<= 1) {
        int t = (tid >= off) ? s[tid - off] : 0;
        __syncthreads();
        s[tid] += t;
        __syncthreads();
    }
    mat[bin * NBLKA + tid] = s[tid] - v;        // exclusive within bucket
    if (tid == 255) total[bin] = s[255];
}

// ---------------- S2: scan bucket totals -> coarse_base[NBKT+1] ----------------

__global__ __launch_bounds__(512) void k_scanTot(const int* __restrict__ total,
                                                 int* __restrict__ cbase) {
    __shared__ int s[512];
    const int tid = threadIdx.x;
    int v = (tid < NBKT) ? total[tid] : 0;
    s[tid] = v;
    __syncthreads();
    for (int off = 1; off < 512; off <<= 1) {
        int t = (tid >= off) ? s[tid - off] : 0;
        __syncthreads();
        s[tid] += t;
        __syncthreads();
    }
    if (tid <= NBKT) cbase[tid] = s[tid] - v;   // tid==NBKT: v=0 -> = E
}

// ---------------- pass B: scatter edges into coarse buckets (LDS cursors only) ----------------

__global__ __launch_bounds__(256) void k_scatterB(const int* __restrict__ ei,
                                                  const float* __restrict__ ew,
                                                  const int* __restrict__ mat,
                                                  const int* __restrict__ cbase,
                                                  int2* __restrict__ tmpA,
                                                  unsigned char* __restrict__ tmpD) {
    __shared__ int cur[NBKT];
    const int tid = threadIdx.x, blk = blockIdx.x;
    for (int i = tid; i < NBKT; i += 256)
        cur[i] = cbase[i] + mat[i * NBLKA + blk];
    __syncthreads();
    const int e0 = blk * EPB, e1 = e0 + EPB;
    for (int e = e0 + tid; e < e1; e += 256) {
        int r = ei[e];
        int c = ei[N_EDGES + e];
        int slot = atomicAdd(&cur[c >> 8], 1);
        tmpA[slot] = make_int2(r, __float_as_int(ew[e]));
        tmpD[slot] = (unsigned char)(c & 255);
    }
}

// ---------------- pass C: per-bucket fine count + scan + CSR emit + dinv (deg fused) ----------------

__global__ __launch_bounds__(256) void k_bucketC(const int* __restrict__ cbase,
                                                 const int2* __restrict__ tmpA,
                                                 const unsigned char* __restrict__ tmpD,
                                                 int2* __restrict__ csr,
                                                 int* __restrict__ cnt,
                                                 int* __restrict__ base,
                                                 float* __restrict__ dinv) {
    __shared__ int   c_cnt[256];
    __shared__ float c_deg[256];
    __shared__ int   c_scan[256];
    __shared__ int   c_cur[256];
    const int tid = threadIdx.x, b = blockIdx.x;
    const int s = cbase[b], e = cbase[b + 1];
    c_cnt[tid] = 0;
    c_deg[tid] = 0.f;
    __syncthreads();
    for (int j = s + tid; j < e; j += 256) {
        int d = tmpD[j];
        atomicAdd(&c_cnt[d], 1);
        atomicAdd(&c_deg[d], __int_as_float(tmpA[j].y));
    }
    __syncthreads();
    int v = c_cnt[tid];
    c_scan[tid] = v;
    __syncthreads();
    for (int off = 1; off < 256; off <<= 1) {
        int t = (tid >= off) ? c_scan[tid - off] : 0;
        __syncthreads();
        c_scan[tid] += t;
        __syncthreads();
    }
    int excl = c_scan[tid] - v;
    c_cur[tid] = excl;
    int node = b * 256 + tid;
    if (node < N_NODES) {
        cnt[node]  = v;
        base[node] = s + excl;
        dinv[node] = rsqrtf(1.0f + c_deg[tid]);   // self-loop weight 1
    }
    __syncthreads();
    for (int j = s + tid; j < e; j += 256) {
        int d = tmpD[j];
        int slot = atomicAdd(&c_cur[d], 1);
        csr[s + slot] = tmpA[j];
    }
}

// ---------------- layer 1 GEMM via MFMA: hpre(bf16) = x @ W1 ----------------
// Block = 4 waves; wave = 16 rows x 64 cols, K=512. W1^T bf16 in LDS (64 KB),
// k-block XOR swizzle. A-frags from global in MFMA layout, cvt bf16 in-reg.

__global__ __launch_bounds__(256) void k_gemm1(const float* __restrict__ x,
                                               const float* __restrict__ W1,
                                               unsigned short* __restrict__ hpre) {
    __shared__ __align__(16) short Wt[64 * 512];   // 65536 B
    const int tid = threadIdx.x;

    {
        const int c  = tid & 63;
        const int kb = (tid >> 6) * 128;
        const int sw = (c & 7) << 3;
        for (int kk = 0; kk < 128; kk += 8) {
            short8 v;
#pragma unroll
            for (int j = 0; j < 8; j++)
                v[j] = (short)f2bf(W1[(size_t)(kb + kk + j) * D_HID + c]);
            *(short8*)&Wt[c * 512 + ((kb + kk) ^ sw)] = v;
        }
    }
    __syncthreads();

    const int widx = blockIdx.x * 4 + (tid >> 6);
    if (widx >= N_NODES / 16) return;
    const int lane = tid & 63;
    const int q  = lane >> 4;
    const int cn = lane & 15;
    const int r0 = widx * 16;
    const int sw = (cn & 7) << 3;

    floatx4 acc[4] = {{0,0,0,0},{0,0,0,0},{0,0,0,0},{0,0,0,0}};
    const float* xp = x + (size_t)(r0 + cn) * D_FEAT + q * 8;

#pragma unroll 4
    for (int k0 = 0; k0 < D_FEAT; k0 += 32) {
        float4 xa = *(const float4*)(xp + k0);
        float4 xb = *(const float4*)(xp + k0 + 4);
        short8 a = pack_bf16x8(xa, xb);
#pragma unroll
        for (int ct = 0; ct < 4; ct++) {
            short8 b = *(const short8*)&Wt[(ct * 16 + cn) * 512 + ((k0 + q * 8) ^ sw)];
            acc[ct] = __builtin_amdgcn_mfma_f32_16x16x32_bf16(a, b, acc[ct], 0, 0, 0);
        }
    }

#pragma unroll
    for (int ct = 0; ct < 4; ct++)
#pragma unroll
        for (int i = 0; i < 4; i++)
            hpre[(size_t)(r0 + q * 4 + i) * D_HID + ct * 16 + cn] = f2bf(acc[ct][i]);
}

// ---------------- layer 1 gather ----------------

__global__ __launch_bounds__(256) void k_gather1(const int* __restrict__ base,
                                                 const int* __restrict__ cnt,
                                                 const int2* __restrict__ csr,
                                                 const unsigned short* __restrict__ hpre,
                                                 const float* __restrict__ dinv,
                                                 float* __restrict__ agg1) {
    int lane = threadIdx.x & 63;
    int n = blockIdx.x * 4 + (threadIdx.x >> 6);
    int s = base[n], e = s + cnt[n];
    float dn = dinv[n];
    float a0 = dn * bf2f(hpre[(size_t)n * D_HID + lane]);
    float a1 = 0.f, a2 = 0.f, a3 = 0.f, a4 = 0.f, a5 = 0.f, a6 = 0.f, a7 = 0.f;
    int j = s;
    for (; j + 7 < e; j += 8) {
        int2 p0 = csr[j];     int2 p1 = csr[j + 1];
        int2 p2 = csr[j + 2]; int2 p3 = csr[j + 3];
        int2 p4 = csr[j + 4]; int2 p5 = csr[j + 5];
        int2 p6 = csr[j + 6]; int2 p7 = csr[j + 7];
        float w0 = dinv[p0.x] * __int_as_float(p0.y);
        float w1 = dinv[p1.x] * __int_as_float(p1.y);
        float w2 = dinv[p2.x] * __int_as_float(p2.y);
        float w3 = dinv[p3.x] * __int_as_float(p3.y);
        float w4 = dinv[p4.x] * __int_as_float(p4.y);
        float w5 = dinv[p5.x] * __int_as_float(p5.y);
        float w6 = dinv[p6.x] * __int_as_float(p6.y);
        float w7 = dinv[p7.x] * __int_as_float(p7.y);
        a0 += w0 * bf2f(hpre[(size_t)p0.x * D_HID + lane]);
        a1 += w1 * bf2f(hpre[(size_t)p1.x * D_HID + lane]);
        a2 += w2 * bf2f(hpre[(size_t)p2.x * D_HID + lane]);
        a3 += w3 * bf2f(hpre[(size_t)p3.x * D_HID + lane]);
        a4 += w4 * bf2f(hpre[(size_t)p4.x * D_HID + lane]);
        a5 += w5 * bf2f(hpre[(size_t)p5.x * D_HID + lane]);
        a6 += w6 * bf2f(hpre[(size_t)p6.x * D_HID + lane]);
        a7 += w7 * bf2f(hpre[(size_t)p7.x * D_HID + lane]);
    }
    for (; j + 3 < e; j += 4) {
        int2 p0 = csr[j];     int2 p1 = csr[j + 1];
        int2 p2 = csr[j + 2]; int2 p3 = csr[j + 3];
        float w0 = dinv[p0.x] * __int_as_float(p0.y);
        float w1 = dinv[p1.x] * __int_as_float(p1.y);
        float w2 = dinv[p2.x] * __int_as_float(p2.y);
        float w3 = dinv[p3.x] * __int_as_float(p3.y);
        a0 += w0 * bf2f(hpre[(size_t)p0.x * D_HID + lane]);
        a1 += w1 * bf2f(hpre[(size_t)p1.x * D_HID + lane]);
        a2 += w2 * bf2f(hpre[(size_t)p2.x * D_HID + lane]);
        a3 += w3 * bf2f(hpre[(size_t)p3.x * D_HID + lane]);
    }
    for (; j < e; j++) {
        int2 p = csr[j];
        a0 += dinv[p.x] * __int_as_float(p.y) * bf2f(hpre[(size_t)p.x * D_HID + lane]);
    }
    agg1[(size_t)n * D_HID + lane] = dn * (((a0 + a1) + (a2 + a3)) + ((a4 + a5) + (a6 + a7)));
}

// ---------------- layer 2 GEMM: z = relu(agg1 + b1) @ W2 ----------------

__global__ __launch_bounds__(256) void k_gemm2(const float* __restrict__ agg1,
                                               const float* __restrict__ b1,
                                               const float* __restrict__ W2,
                                               float* __restrict__ z) {
    int gid = blockIdx.x * 256 + threadIdx.x;
    int n = gid / N_CLS;
    int c = gid - n * N_CLS;
    const float* ap = agg1 + (size_t)n * D_HID;
    float acc = 0.f;
#pragma unroll 8
    for (int k = 0; k < D_HID; k++) {
        float h = ap[k] + b1[k];
        h = h > 0.f ? h : 0.f;
        acc += h * W2[k * N_CLS + c];
    }
    z[gid] = acc;
}

// ---------------- layer 2 gather + bias + log_softmax fused ----------------

__global__ __launch_bounds__(256) void k_gather2_lsm(const int* __restrict__ base,
                                                     const int* __restrict__ cnt,
                                                     const int2* __restrict__ csr,
                                                     const float* __restrict__ z,
                                                     const float* __restrict__ dinv,
                                                     const float* __restrict__ b2,
                                                     float* __restrict__ out) {
    int lane = threadIdx.x & 63;
    int n = blockIdx.x * 4 + (threadIdx.x >> 6);
    bool act = lane < N_CLS;
    int fl = act ? lane : (N_CLS - 1);          // clamped lane for safe loads
    int s = base[n], e = s + cnt[n];
    float dn = dinv[n];
    float a0 = dn * z[(size_t)n * N_CLS + fl];
    float a1 = 0.f, a2 = 0.f, a3 = 0.f, a4 = 0.f, a5 = 0.f, a6 = 0.f, a7 = 0.f;
    int j = s;
    for (; j + 7 < e; j += 8) {
        int2 p0 = csr[j];     int2 p1 = csr[j + 1];
        int2 p2 = csr[j + 2]; int2 p3 = csr[j + 3];
        int2 p4 = csr[j + 4]; int2 p5 = csr[j + 5];
        int2 p6 = csr[j + 6]; int2 p7 = csr[j + 7];
        float w0 = dinv[p0.x] * __int_as_float(p0.y);
        float w1 = dinv[p1.x] * __int_as_float(p1.y);
        float w2 = dinv[p2.x] * __int_as_float(p2.y);
        float w3 = dinv[p3.x] * __int_as_float(p3.y);
        float w4 = dinv[p4.x] * __int_as_float(p4.y);
        float w5 = dinv[p5.x] * __int_as_float(p5.y);
        float w6 = dinv[p6.x] * __int_as_float(p6.y);
        float w7 = dinv[p7.x] * __int_as_float(p7.y);
        a0 += w0 * z[(size_t)p0.x * N_CLS + fl];
        a1 += w1 * z[(size_t)p1.x * N_CLS + fl];
        a2 += w2 * z[(size_t)p2.x * N_CLS + fl];
        a3 += w3 * z[(size_t)p3.x * N_CLS + fl];
        a4 += w4 * z[(size_t)p4.x * N_CLS + fl];
        a5 += w5 * z[(size_t)p5.x * N_CLS + fl];
        a6 += w6 * z[(size_t)p6.x * N_CLS + fl];
        a7 += w7 * z[(size_t)p7.x * N_CLS + fl];
    }
    for (; j + 3 < e; j += 4) {
        int2 p0 = csr[j];     int2 p1 = csr[j + 1];
        int2 p2 = csr[j + 2]; int2 p3 = csr[j + 3];
        float w0 = dinv[p0.x] * __int_as_float(p0.y);
        float w1 = dinv[p1.x] * __int_as_float(p1.y);
        float w2 = dinv[p2.x] * __int_as_float(p2.y);
        float w3 = dinv[p3.x] * __int_as_float(p3.y);
        a0 += w0 * z[(size_t)p0.x * N_CLS + fl];
        a1 += w1 * z[(size_t)p1.x * N_CLS + fl];
        a2 += w2 * z[(size_t)p2.x * N_CLS + fl];
        a3 += w3 * z[(size_t)p3.x * N_CLS + fl];
    }
    for (; j < e; j++) {
        int2 p = csr[j];
        a0 += dinv[p.x] * __int_as_float(p.y) * z[(size_t)p.x * N_CLS + fl];
    }
    float logit = dn * (((a0 + a1) + (a2 + a3)) + ((a4 + a5) + (a6 + a7))) + b2[fl];
    float m = act ? logit : -INFINITY;
    for (int off = 32; off; off >>= 1) m = fmaxf(m, __shfl_xor(m, off, 64));
    float ev = act ? expf(logit - m) : 0.f;
    float sum = ev;
    for (int off = 32; off; off >>= 1) sum += __shfl_xor(sum, off, 64);
    if (act) out[(size_t)n * N_CLS + lane] = logit - m - logf(sum);
}

// ---------------- launch ----------------

extern "C" void kernel_launch(void* const* d_in, const int* in_sizes, int n_in,
                              void* d_out, int out_size, void* d_ws, size_t ws_size,
                              hipStream_t stream) {
    const float* x  = (const float*)d_in[0];
    const int*   ei = (const int*)d_in[1];
    const float* ew = (const float*)d_in[2];
    const float* W1 = (const float*)d_in[3];
    const float* b1 = (const float*)d_in[4];
    const float* W2 = (const float*)d_in[5];
    const float* b2 = (const float*)d_in[6];
    float* out = (float*)d_out;

    // workspace layout (4B words):
    //   [0,      6.4M)  csr   int2[E]
    //   [6.4M,  12.8M)  tmpA  int2[E]   -- dead after C; hpre at [6.4M, 8.0M), z at [8.0M, 12.0M)
    //   [12.8M, 13.6M)  tmpD  uchar[E]
    //   then mat / total / cbase / cnt / base / dinv / agg1
    int* ws = (int*)d_ws;
    int2*          csr  = (int2*)ws;
    int2*          tmpA = (int2*)(ws + 2 * (size_t)N_EDGES);
    unsigned char* tmpD = (unsigned char*)(ws + 4 * (size_t)N_EDGES);
    int*   mat   = ws + 4 * (size_t)N_EDGES + N_EDGES / 4;
    int*   total = mat + NBKT * NBLKA;
    int*   cbase = total + NBKT;
    int*   cnt   = cbase + NBKT + 1;
    int*   base  = cnt + N_NODES;
    float* dinv  = (float*)(base + N_NODES);
    float* agg1  = dinv + N_NODES;
    unsigned short* hpre = (unsigned short*)tmpA;              // alias: tmpA dead after C
    float* z = (float*)(ws + 2 * (size_t)N_EDGES + 2 * (size_t)N_NODES * D_HID / 2 + (size_t)N_NODES * D_HID / 2);
    // simpler: z right after hpre inside the tmpA region:
    z = (float*)(hpre + (size_t)N_NODES * D_HID);              // 4M words, ends at 12.0M < 12.8M ✓

    k_histA   <<<NBLKA, 256, 0, stream>>>(ei, mat);
    k_scanRows<<<NBKT,  256, 0, stream>>>(mat, total);
    k_scanTot <<<1,     512, 0, stream>>>(total, cbase);
    k_scatterB<<<NBLKA, 256, 0, stream>>>(ei, ew, mat, cbase, tmpA, tmpD);
    k_bucketC <<<NBKT,  256, 0, stream>>>(cbase, tmpA, tmpD, csr, cnt, base, dinv);
    k_gemm1   <<<(N_NODES / 16 + 3) / 4, 256, 0, stream>>>(x, W1, hpre);
    k_gather1 <<<N_NODES / 4, 256, 0, stream>>>(base, cnt, csr, hpre, dinv, agg1);
    k_gemm2   <<<N_NODES * N_CLS / 256, 256, 0, stream>>>(agg1, b1, W2, z);
    k_gather2_lsm<<<N_NODES / 4, 256, 0, stream>>>(base, cnt, csr, z, dinv, b2, out);
}